// Round 3
// baseline (1705.871 us; speedup 1.0000x reference)
//
#include <hip/hip_runtime.h>
#include <math.h>

#define NN 50000
#define NE 800000

__device__ __forceinline__ float silu(float x) { return x / (1.0f + expf(-x)); }

// Zero-cost ordering fence: forbids the compiler from moving LDS ops across,
// regardless of aliasing conclusions. HW DS pipe is in-order per wave.
__device__ __forceinline__ void wave_fence() {
    asm volatile("" ::: "memory");
    __builtin_amdgcn_wave_barrier();
    asm volatile("" ::: "memory");
}

// ---------------- Kernel 1: per-node gate scalars gx = mlp(h;nx), gv = mlp(h;nv)
// Activations live in registers; cross-lane via __shfl. No LDS hazards.
__global__ __launch_bounds__(256) void node_gate_kernel(
    const float* __restrict__ h,
    const float* __restrict__ nx_w1, const float* __restrict__ nx_b1,
    const float* __restrict__ nx_w2, const float* __restrict__ nx_b2,
    const float* __restrict__ nv_w1, const float* __restrict__ nv_b1,
    const float* __restrict__ nv_w2, const float* __restrict__ nv_b2,
    float* __restrict__ gx, float* __restrict__ gv)
{
    __shared__ float wx[64 * 64];
    __shared__ float wv[64 * 64];
    __shared__ float wx2[64], wv2[64], bx1[64], bv1[64];
    int tid = threadIdx.x;
    for (int i = tid; i < 64 * 64; i += 256) { wx[i] = nx_w1[i]; wv[i] = nv_w1[i]; }
    if (tid < 64) { wx2[tid] = nx_w2[tid]; wv2[tid] = nv_w2[tid]; bx1[tid] = nx_b1[tid]; bv1[tid] = nv_b1[tid]; }
    __syncthreads();
    float bx2 = nx_b2[0], bv2 = nv_b2[0];
    int wave = tid >> 6, lane = tid & 63;
    for (int node = blockIdx.x * 4 + wave; node < NN; node += gridDim.x * 4) {
        float hv = h[(long)node * 64 + lane];
        float ax = bx1[lane], av = bv1[lane];
        #pragma unroll
        for (int k = 0; k < 64; ++k) {
            float hk = __shfl(hv, k);
            ax = fmaf(hk, wx[k * 64 + lane], ax);
            av = fmaf(hk, wv[k * 64 + lane], av);
        }
        float px = silu(ax) * wx2[lane];
        float pv = silu(av) * wv2[lane];
        #pragma unroll
        for (int off = 32; off; off >>= 1) { px += __shfl_xor(px, off); pv += __shfl_xor(pv, off); }
        if (lane == 0) { gx[node] = px + bx2; gv[node] = pv + bv2; }
    }
}

// ---------------- Kernel 2: edge MLPs + atomic scatter (the hot kernel)
__global__ __launch_bounds__(256) void edge_kernel(
    const float* __restrict__ x, const float* __restrict__ h, const float* __restrict__ v,
    const int* __restrict__ row, const int* __restrict__ col,
    const float* __restrict__ edge_fea,
    const float* __restrict__ em_w1, const float* __restrict__ em_b1,
    const float* __restrict__ em_w2, const float* __restrict__ em_b2,
    const float* __restrict__ cn_w1, const float* __restrict__ cn_b1,
    const float* __restrict__ cn_w2, const float* __restrict__ cn_b2,
    float* __restrict__ cnt, double* __restrict__ totf, float* __restrict__ totmsg)
{
    __shared__ float w1s[148 * 64];          // em_w1, rows 146..147 zero-padded
    __shared__ float w2s[64 * 64];           // em_w2
    __shared__ float c1s[64 * 64];           // cn_w1
    __shared__ float c2s[64];                // cn_w2
    __shared__ float b1s[64], b2s[64], cb1s[64];
    __shared__ __align__(16) float sbuf[4][2][148];  // scalar_in per wave x 2 edges
    __shared__ __align__(16) float ybuf[4][2][64];   // hidden activations (y, then msg)

    int tid = threadIdx.x;
    for (int i = tid; i < 146 * 64; i += 256) w1s[i] = em_w1[i];
    for (int i = 146 * 64 + tid; i < 148 * 64; i += 256) w1s[i] = 0.0f;
    for (int i = tid; i < 64 * 64; i += 256) { w2s[i] = em_w2[i]; c1s[i] = cn_w1[i]; }
    if (tid < 64) { c2s[tid] = cn_w2[tid]; b1s[tid] = em_b1[tid]; b2s[tid] = em_b2[tid]; cb1s[tid] = cn_b1[tid]; }
    __syncthreads();
    float cb2 = cn_b2[0];

    int wave = tid >> 6, lane = tid & 63;
    if (lane == 0) {  // zero-pad scalar_in tails once (wave-private, never rewritten)
        sbuf[wave][0][146] = 0.f; sbuf[wave][0][147] = 0.f;
        sbuf[wave][1][146] = 0.f; sbuf[wave][1][147] = 0.f;
    }

    const int npairs = NE / 2;
    for (int pair = blockIdx.x * 4 + wave; pair < npairs; pair += gridDim.x * 4) {
        int e0 = pair * 2;
        int r0 = row[e0], c0 = col[e0];
        int r1 = row[e0 + 1], c1 = col[e0 + 1];

        // ---- stage scalar_in into LDS
        sbuf[wave][0][2 + lane]  = h[(long)r0 * 64 + lane];
        sbuf[wave][0][66 + lane] = h[(long)c0 * 64 + lane];
        sbuf[wave][1][2 + lane]  = h[(long)r1 * 64 + lane];
        sbuf[wave][1][66 + lane] = h[(long)c1 * 64 + lane];
        if (lane < 32) sbuf[wave][lane >> 4][130 + (lane & 15)] = edge_fea[(long)e0 * 16 + lane];

        const float* xr0 = x + r0 * 3; const float* xc0 = x + c0 * 3;
        const float* vr0 = v + r0 * 3; const float* vc0 = v + c0 * 3;
        const float* xr1 = x + r1 * 3; const float* xc1 = x + c1 * 3;
        const float* vr1 = v + r1 * 3; const float* vc1 = v + c1 * 3;
        float rx0 = xr0[0] - xc0[0], ry0 = xr0[1] - xc0[1], rz0 = xr0[2] - xc0[2];
        float sx0 = vr0[0] - vc0[0], sy0 = vr0[1] - vc0[1], sz0 = vr0[2] - vc0[2];
        float rx1 = xr1[0] - xc1[0], ry1 = xr1[1] - xc1[1], rz1 = xr1[2] - xc1[2];
        float sx1 = vr1[0] - vc1[0], sy1 = vr1[1] - vc1[1], sz1 = vr1[2] - vc1[2];
        float nr0 = sqrtf(rx0 * rx0 + ry0 * ry0 + rz0 * rz0);
        float ns0 = sqrtf(sx0 * sx0 + sy0 * sy0 + sz0 * sz0);
        float nr1 = sqrtf(rx1 * rx1 + ry1 * ry1 + rz1 * rz1);
        float ns1 = sqrtf(sx1 * sx1 + sy1 * sy1 + sz1 * sz1);
        if (lane == 0) {
            sbuf[wave][0][0] = nr0; sbuf[wave][0][1] = ns0;
            sbuf[wave][1][0] = nr1; sbuf[wave][1][1] = ns1;
        }
        wave_fence();  // staging writes complete (program order) before reads below

        // ---- em layer 1: 148 (padded) -> 64
        float a0 = b1s[lane], a1 = b1s[lane];
        const float4* s0 = (const float4*)sbuf[wave][0];
        const float4* s1 = (const float4*)sbuf[wave][1];
        for (int k4 = 0; k4 < 37; ++k4) {
            float4 q0 = s0[k4], q1 = s1[k4];
            const float* wk = &w1s[k4 * 256 + lane];
            float w0 = wk[0], w64 = wk[64], w128 = wk[128], w192 = wk[192];
            a0 += q0.x * w0;   a1 += q1.x * w0;
            a0 += q0.y * w64;  a1 += q1.y * w64;
            a0 += q0.z * w128; a1 += q1.z * w128;
            a0 += q0.w * w192; a1 += q1.w * w192;
        }
        ybuf[wave][0][lane] = silu(a0);
        ybuf[wave][1][lane] = silu(a1);
        wave_fence();

        // ---- em layer 2: 64 -> 64, then silu (last_act=True) -> message
        float m0 = b2s[lane], m1 = b2s[lane];
        {
            const float4* y0 = (const float4*)ybuf[wave][0];
            const float4* y1 = (const float4*)ybuf[wave][1];
            for (int k4 = 0; k4 < 16; ++k4) {
                float4 q0 = y0[k4], q1 = y1[k4];
                const float* wk = &w2s[k4 * 256 + lane];
                float w0 = wk[0], w64 = wk[64], w128 = wk[128], w192 = wk[192];
                m0 += q0.x * w0;   m1 += q1.x * w0;
                m0 += q0.y * w64;  m1 += q1.y * w64;
                m0 += q0.z * w128; m1 += q1.z * w128;
                m0 += q0.w * w192; m1 += q1.w * w192;
            }
        }
        m0 = silu(m0); m1 = silu(m1);
        wave_fence();  // layer-2 reads of ybuf done before overwrite
        ybuf[wave][0][lane] = m0;
        ybuf[wave][1][lane] = m1;
        wave_fence();

        // ---- cn layer 1: 64 -> 64 silu
        float t0 = cb1s[lane], t1 = cb1s[lane];
        {
            const float4* p0 = (const float4*)ybuf[wave][0];
            const float4* p1 = (const float4*)ybuf[wave][1];
            for (int k4 = 0; k4 < 16; ++k4) {
                float4 q0 = p0[k4], q1 = p1[k4];
                const float* wk = &c1s[k4 * 256 + lane];
                float w0 = wk[0], w64 = wk[64], w128 = wk[128], w192 = wk[192];
                t0 += q0.x * w0;   t1 += q1.x * w0;
                t0 += q0.y * w64;  t1 += q1.y * w64;
                t0 += q0.z * w128; t1 += q1.z * w128;
                t0 += q0.w * w192; t1 += q1.w * w192;
            }
        }
        // ---- cn layer 2: dot(silu(t), cn_w2) + cn_b2  (wave reduce)
        float u0 = silu(t0) * c2s[lane];
        float u1 = silu(t1) * c2s[lane];
        #pragma unroll
        for (int off = 32; off; off >>= 1) { u0 += __shfl_xor(u0, off); u1 += __shfl_xor(u1, off); }
        float cm0 = u0 + cb2, cm1 = u1 + cb2;

        // ---- scatter: count (f32, exact), tot_f (f64 atomics), tot_message (f32)
        if (lane < 3) {
            float comp = (lane == 0) ? rx0 : (lane == 1) ? ry0 : rz0;
            atomicAdd(&totf[(long)r0 * 3 + lane], (double)(comp * cm0));
        } else if (lane == 3) {
            atomicAdd(&cnt[r0], 1.0f);
        } else if (lane >= 8 && lane < 11) {
            int l = lane - 8;
            float comp = (l == 0) ? rx1 : (l == 1) ? ry1 : rz1;
            atomicAdd(&totf[(long)r1 * 3 + l], (double)(comp * cm1));
        } else if (lane == 11) {
            atomicAdd(&cnt[r1], 1.0f);
        }
        atomicAdd(&totmsg[(long)r0 * 64 + lane], m0);
        atomicAdd(&totmsg[(long)r1 * 64 + lane], m1);
    }
}

// ---------------- Kernel 3: finalize nodes (register/shfl activations, no LDS hazards)
__global__ __launch_bounds__(256) void node_out_kernel(
    const float* __restrict__ x, const float* __restrict__ h, const float* __restrict__ v,
    const float* __restrict__ nn_w1, const float* __restrict__ nn_b1,
    const float* __restrict__ nn_w2, const float* __restrict__ nn_b2,
    const float* __restrict__ cnt, const double* __restrict__ totf,
    const float* __restrict__ totmsg,
    const float* __restrict__ gx, const float* __restrict__ gv,
    float* __restrict__ xout, float* __restrict__ vout, float* __restrict__ hout)
{
    __shared__ float w1s[128 * 64];  // 32KB
    __shared__ float w2s[64 * 64];   // 16KB
    __shared__ float b1s[64], b2s[64];
    int tid = threadIdx.x;
    for (int i = tid; i < 128 * 64; i += 256) w1s[i] = nn_w1[i];
    for (int i = tid; i < 64 * 64; i += 256) w2s[i] = nn_w2[i];
    if (tid < 64) { b1s[tid] = nn_b1[tid]; b2s[tid] = nn_b2[tid]; }
    __syncthreads();
    int wave = tid >> 6, lane = tid & 63;
    for (int node = blockIdx.x * 4 + wave; node < NN; node += gridDim.x * 4) {
        float hv = h[(long)node * 64 + lane];
        float tm = totmsg[(long)node * 64 + lane];
        float a = b1s[lane];
        #pragma unroll
        for (int k = 0; k < 64; ++k)
            a = fmaf(__shfl(hv, k), w1s[k * 64 + lane], a);
        #pragma unroll
        for (int k = 0; k < 64; ++k)
            a = fmaf(__shfl(tm, k), w1s[(64 + k) * 64 + lane], a);
        float y = silu(a);
        float o = b2s[lane];
        #pragma unroll
        for (int k = 0; k < 64; ++k)
            o = fmaf(__shfl(y, k), w2s[k * 64 + lane], o);
        hout[(long)node * 64 + lane] = o;
        if (lane < 3) {
            double dn = fmax((double)cnt[node], 1.0);
            double tf = totf[(long)node * 3 + lane] / dn;
            tf = fmin(fmax(tf, -100.0), 100.0);
            xout[(long)node * 3 + lane] = gx[node] * x[(long)node * 3 + lane] + (float)tf;
            vout[(long)node * 3 + lane] = gv[node] * v[(long)node * 3 + lane] + (float)tf;
        }
    }
}

extern "C" void kernel_launch(void* const* d_in, const int* in_sizes, int n_in,
                              void* d_out, int out_size, void* d_ws, size_t ws_size,
                              hipStream_t stream) {
    const float* x        = (const float*)d_in[0];
    const float* h        = (const float*)d_in[1];
    const float* v        = (const float*)d_in[2];
    const int*   eidx     = (const int*)d_in[3];
    const float* edge_fea = (const float*)d_in[4];
    const float* em_w1 = (const float*)d_in[5];  const float* em_b1 = (const float*)d_in[6];
    const float* em_w2 = (const float*)d_in[7];  const float* em_b2 = (const float*)d_in[8];
    const float* cn_w1 = (const float*)d_in[9];  const float* cn_b1 = (const float*)d_in[10];
    const float* cn_w2 = (const float*)d_in[11]; const float* cn_b2 = (const float*)d_in[12];
    const float* nn_w1 = (const float*)d_in[13]; const float* nn_b1 = (const float*)d_in[14];
    const float* nn_w2 = (const float*)d_in[15]; const float* nn_b2 = (const float*)d_in[16];
    const float* nx_w1 = (const float*)d_in[17]; const float* nx_b1 = (const float*)d_in[18];
    const float* nx_w2 = (const float*)d_in[19]; const float* nx_b2 = (const float*)d_in[20];
    const float* nv_w1 = (const float*)d_in[21]; const float* nv_b1 = (const float*)d_in[22];
    const float* nv_w2 = (const float*)d_in[23]; const float* nv_b2 = (const float*)d_in[24];

    const int* row = eidx;
    const int* col = eidx + NE;

    // Workspace layout (f32 units):
    //   cnt    [0, N)
    //   gx     [N, 2N)
    //   gv     [2N, 3N)
    //   totmsg [3N, 67N)
    //   totf   [68N, 74N)   (3N doubles, 8B-aligned)
    float*  ws     = (float*)d_ws;
    float*  cnt    = ws;
    float*  gx     = ws + NN;
    float*  gv     = ws + 2 * NN;
    float*  totmsg = ws + 3 * NN;
    double* totf   = (double*)(ws + 68 * NN);

    float* xout = (float*)d_out;
    float* vout = xout + NN * 3;
    float* hout = vout + NN * 3;

    // zero all accumulators (cnt, totmsg, totf; gx/gv fully overwritten)
    hipMemsetAsync(d_ws, 0, (size_t)74 * NN * sizeof(float), stream);

    node_gate_kernel<<<1024, 256, 0, stream>>>(h, nx_w1, nx_b1, nx_w2, nx_b2,
                                               nv_w1, nv_b1, nv_w2, nv_b2, gx, gv);
    edge_kernel<<<1024, 256, 0, stream>>>(x, h, v, row, col, edge_fea,
                                          em_w1, em_b1, em_w2, em_b2,
                                          cn_w1, cn_b1, cn_w2, cn_b2,
                                          cnt, totf, totmsg);
    node_out_kernel<<<1024, 256, 0, stream>>>(x, h, v, nn_w1, nn_b1, nn_w2, nn_b2,
                                              cnt, totf, totmsg, gx, gv,
                                              xout, vout, hout);
}

// Round 10
// 914.937 us; speedup vs baseline: 1.8645x; 1.8645x over previous
//
#include <hip/hip_runtime.h>
#include <math.h>

#define NN 50000
#define NE 800000

typedef __attribute__((ext_vector_type(8))) short  s16x8;  // 8 bf16 (4 VGPRs) MFMA A/B frag
typedef __attribute__((ext_vector_type(4))) float  f32x4;  // MFMA C/D frag

__device__ __forceinline__ float silu(float x) { return x / (1.0f + expf(-x)); }

__device__ __forceinline__ unsigned short f2bf(float f) {  // RNE f32->bf16
    unsigned u = __builtin_bit_cast(unsigned, f);
    u += 0x7FFFu + ((u >> 16) & 1u);
    return (unsigned short)(u >> 16);
}
__device__ __forceinline__ float bf2f(unsigned short b) {
    unsigned u = ((unsigned)b) << 16;
    return __builtin_bit_cast(float, u);
}

// Zero-cost ordering fence: forbids compiler reordering of LDS ops across it.
// HW DS pipe is in-order per wave.
__device__ __forceinline__ void wave_fence() {
    asm volatile("" ::: "memory");
    __builtin_amdgcn_wave_barrier();
    asm volatile("" ::: "memory");
}

// ---------------- Kernel 1: per-node gate scalars gx = mlp(h;nx), gv = mlp(h;nv)
__global__ __launch_bounds__(256) void node_gate_kernel(
    const float* __restrict__ h,
    const float* __restrict__ nx_w1, const float* __restrict__ nx_b1,
    const float* __restrict__ nx_w2, const float* __restrict__ nx_b2,
    const float* __restrict__ nv_w1, const float* __restrict__ nv_b1,
    const float* __restrict__ nv_w2, const float* __restrict__ nv_b2,
    float* __restrict__ gx, float* __restrict__ gv)
{
    __shared__ float wx[64 * 64];
    __shared__ float wv[64 * 64];
    __shared__ float wx2[64], wv2[64], bx1[64], bv1[64];
    int tid = threadIdx.x;
    for (int i = tid; i < 64 * 64; i += 256) { wx[i] = nx_w1[i]; wv[i] = nv_w1[i]; }
    if (tid < 64) { wx2[tid] = nx_w2[tid]; wv2[tid] = nv_w2[tid]; bx1[tid] = nx_b1[tid]; bv1[tid] = nv_b1[tid]; }
    __syncthreads();
    float bx2 = nx_b2[0], bv2 = nv_b2[0];
    int wave = tid >> 6, lane = tid & 63;
    for (int node = blockIdx.x * 4 + wave; node < NN; node += gridDim.x * 4) {
        float hv = h[(long)node * 64 + lane];
        float ax = bx1[lane], av = bv1[lane];
        #pragma unroll
        for (int k = 0; k < 64; ++k) {
            float hk = __shfl(hv, k);
            ax = fmaf(hk, wx[k * 64 + lane], ax);
            av = fmaf(hk, wv[k * 64 + lane], av);
        }
        float px = silu(ax) * wx2[lane];
        float pv = silu(av) * wv2[lane];
        #pragma unroll
        for (int off = 32; off; off >>= 1) { px += __shfl_xor(px, off); pv += __shfl_xor(pv, off); }
        if (lane == 0) { gx[node] = px + bx2; gv[node] = pv + bv2; }
    }
}

// ---------------- Kernel 2: edge MLPs via MFMA + atomic scatter (the hot kernel)
//
// Per-wave 16-edge tiles. scalar_in K-permutation (vs reference order):
//   k' in [0,64)    -> h[row]   (orig rows 2..65)
//   k' in [64,128)  -> h[col]   (orig rows 66..129)
//   k' in [128,144) -> edge_fea (orig rows 130..145)
//   k' in [144,146) -> norms    (orig rows 0..1)
//   k' in [146,168) -> zero pad (K padded to 5 x 32 = 160, stride 168)
// em_w1 rows permuted identically at weight staging, so the product is exact.
#define KPAD   168   // A / w1t K stride (bf16), 16B-aligned (168*2=336)
#define YPITCH 72    // Y / w2t / c1t K stride (bf16), 16B-aligned (144B)

__global__ __launch_bounds__(256, 2) void edge_kernel(
    const float* __restrict__ x, const float* __restrict__ h, const float* __restrict__ v,
    const int* __restrict__ row, const int* __restrict__ col,
    const float* __restrict__ edge_fea,
    const float* __restrict__ em_w1, const float* __restrict__ em_b1,
    const float* __restrict__ em_w2, const float* __restrict__ em_b2,
    const float* __restrict__ cn_w1, const float* __restrict__ cn_b1,
    const float* __restrict__ cn_w2, const float* __restrict__ cn_b2,
    float* __restrict__ cnt, double* __restrict__ totf, float* __restrict__ totmsg)
{
    __shared__ unsigned short w1t[64 * KPAD];     // [n][k'] = em_w1[orig(k')][n], bf16
    __shared__ unsigned short w2t[64 * YPITCH];   // [n][k]  = em_w2[k][n]
    __shared__ unsigned short c1t[64 * YPITCH];   // [n][k]  = cn_w1[k][n]
    __shared__ float b1s[64], b2s[64], cb1s[64], c2s[64];
    __shared__ unsigned short Atile[4][16 * KPAD];    // per-wave A (bf16)
    __shared__ unsigned short Ybuf [4][16 * YPITCH];  // per-wave act/msg (bf16)

    int tid = threadIdx.x;
    // ---- one-time weight staging (transpose + K-permute + bf16)
    for (int idx = tid; idx < 64 * KPAD; idx += 256) {
        int n = idx / KPAD, kp = idx - n * KPAD;
        float val = 0.0f;
        if (kp < 146) { int ko = (kp < 144) ? (kp + 2) : (kp - 144); val = em_w1[ko * 64 + n]; }
        w1t[n * KPAD + kp] = f2bf(val);
    }
    for (int idx = tid; idx < 64 * YPITCH; idx += 256) {
        int n = idx / YPITCH, k = idx - n * YPITCH;
        w2t[idx] = f2bf(k < 64 ? em_w2[k * 64 + n] : 0.0f);
        c1t[idx] = f2bf(k < 64 ? cn_w1[k * 64 + n] : 0.0f);
    }
    if (tid < 64) { b1s[tid] = em_b1[tid]; b2s[tid] = em_b2[tid]; cb1s[tid] = cn_b1[tid]; c2s[tid] = cn_w2[tid]; }
    __syncthreads();
    float cb2 = cn_b2[0];

    int wv = tid >> 6, l = tid & 63;
    int lm = l & 15, lg = l >> 4;

    // ---- cache GEMM2/GEMM3 B-frags in VGPRs (layout: lane holds B[k][n],
    //      n = 16*ns + lm, k = 32*kk + 8*lg + j, j=0..7 contiguous in [n][k] store)
    s16x8 B2[2][4], B3[2][4];
    #pragma unroll
    for (int kk = 0; kk < 2; ++kk)
        #pragma unroll
        for (int ns = 0; ns < 4; ++ns) {
            B2[kk][ns] = *(const s16x8*)&w2t[(16 * ns + lm) * YPITCH + 32 * kk + 8 * lg];
            B3[kk][ns] = *(const s16x8*)&c1t[(16 * ns + lm) * YPITCH + 32 * kk + 8 * lg];
        }

    unsigned short* A = Atile[wv];
    unsigned short* Y = Ybuf[wv];

    // zero-pad region k' in [146,168) — staging never touches it; write once
    if (lg == 0)
        for (int z = 146; z < KPAD; ++z) A[lm * KPAD + z] = 0;
    wave_fence();

    const int ntile = NE / 16;
    for (int tile = blockIdx.x * 4 + wv; tile < ntile; tile += gridDim.x * 4) {
        int base = tile * 16;
        // each lane owns edge (l&15); 4x redundant across lg groups (cheap, enables shfl)
        int r_own = row[base + lm];
        int c_own = col[base + lm];

        // geometry for own edge
        const float* xr = x + (long)r_own * 3; const float* xc = x + (long)c_own * 3;
        const float* vr = v + (long)r_own * 3; const float* vc = v + (long)c_own * 3;
        float rx = xr[0] - xc[0], ry = xr[1] - xc[1], rz = xr[2] - xc[2];
        float sx = vr[0] - vc[0], sy = vr[1] - vc[1], sz = vr[2] - vc[2];
        float nr = sqrtf(rx * rx + ry * ry + rz * rz);
        float nsv = sqrtf(sx * sx + sy * sy + sz * sz);
        if (lg == 0) {
            A[lm * KPAD + 144] = f2bf(nr);
            A[lm * KPAD + 145] = f2bf(nsv);
        }
        // h gather (coalesced 256B per row)
        #pragma unroll 4
        for (int e = 0; e < 16; ++e) {
            int re = __shfl(r_own, e);
            int ce = __shfl(c_own, e);
            A[e * KPAD + l]      = f2bf(h[(long)re * 64 + l]);
            A[e * KPAD + 64 + l] = f2bf(h[(long)ce * 64 + l]);
        }
        // edge features: 16 edges x 16 = 256 contiguous f32
        const float* efb = edge_fea + (long)base * 16;
        #pragma unroll
        for (int i = 0; i < 4; ++i) {
            int idx = i * 64 + l; int e = idx >> 4, j = idx & 15;
            A[e * KPAD + 128 + j] = f2bf(efb[idx]);
        }
        wave_fence();

        // ---- GEMM1: [16 x 160] x [160 x 64] -> acc (f32), bias-init
        f32x4 acc[4];
        #pragma unroll
        for (int ns = 0; ns < 4; ++ns) { float b = b1s[16 * ns + lm]; acc[ns] = (f32x4){b, b, b, b}; }
        #pragma unroll
        for (int kk = 0; kk < 5; ++kk) {
            s16x8 af = *(const s16x8*)&A[lm * KPAD + 32 * kk + 8 * lg];
            #pragma unroll
            for (int ns = 0; ns < 4; ++ns) {
                s16x8 bf = *(const s16x8*)&w1t[(16 * ns + lm) * KPAD + 32 * kk + 8 * lg];
                acc[ns] = __builtin_amdgcn_mfma_f32_16x16x32_bf16(af, bf, acc[ns], 0, 0, 0);
            }
        }
        wave_fence();  // (also orders prior-iter scatter Y-reads before Y writes below)
        // silu -> Y (bf16); D layout: row = 4*lg + i, col = 16*ns + lm
        #pragma unroll
        for (int ns = 0; ns < 4; ++ns)
            #pragma unroll
            for (int i = 0; i < 4; ++i)
                Y[(4 * lg + i) * YPITCH + 16 * ns + lm] = f2bf(silu(acc[ns][i]));
        wave_fence();

        // ---- GEMM2: y[16x64] x em_w2 -> message (silu)
        #pragma unroll
        for (int ns = 0; ns < 4; ++ns) { float b = b2s[16 * ns + lm]; acc[ns] = (f32x4){b, b, b, b}; }
        #pragma unroll
        for (int kk = 0; kk < 2; ++kk) {
            s16x8 af = *(const s16x8*)&Y[lm * YPITCH + 32 * kk + 8 * lg];
            #pragma unroll
            for (int ns = 0; ns < 4; ++ns)
                acc[ns] = __builtin_amdgcn_mfma_f32_16x16x32_bf16(af, B2[kk][ns], acc[ns], 0, 0, 0);
        }
        wave_fence();  // GEMM2 A-reads done before Y overwrite
        #pragma unroll
        for (int ns = 0; ns < 4; ++ns)
            #pragma unroll
            for (int i = 0; i < 4; ++i)
                Y[(4 * lg + i) * YPITCH + 16 * ns + lm] = f2bf(silu(acc[ns][i]));
        wave_fence();

        // ---- GEMM3: msg[16x64] x cn_w1 -> t; cm = dot(silu(t), cn_w2) + cb2
        #pragma unroll
        for (int ns = 0; ns < 4; ++ns) { float b = cb1s[16 * ns + lm]; acc[ns] = (f32x4){b, b, b, b}; }
        #pragma unroll
        for (int kk = 0; kk < 2; ++kk) {
            s16x8 af = *(const s16x8*)&Y[lm * YPITCH + 32 * kk + 8 * lg];
            #pragma unroll
            for (int ns = 0; ns < 4; ++ns)
                acc[ns] = __builtin_amdgcn_mfma_f32_16x16x32_bf16(af, B3[kk][ns], acc[ns], 0, 0, 0);
        }
        float cm[4];
        #pragma unroll
        for (int i = 0; i < 4; ++i) {
            float p = 0.0f;
            #pragma unroll
            for (int ns = 0; ns < 4; ++ns) p += silu(acc[ns][i]) * c2s[16 * ns + lm];
            p += __shfl_xor(p, 1); p += __shfl_xor(p, 2);
            p += __shfl_xor(p, 4); p += __shfl_xor(p, 8);
            cm[i] = p + cb2;   // cm for edge (4*lg + i), valid in all 16 lanes of group lg
        }

        // ---- scatter tot_f (f64) + cnt
        #pragma unroll
        for (int i = 0; i < 4; ++i) {
            int e = 4 * lg + i;
            float rxe = __shfl(rx, e), rye = __shfl(ry, e), rze = __shfl(rz, e);
            int   re  = __shfl(r_own, e);
            if (lm < 3) {
                float comp = (lm == 0) ? rxe : (lm == 1) ? rye : rze;
                atomicAdd(&totf[(long)re * 3 + lm], (double)(comp * cm[i]));
            } else if (lm == 3) {
                atomicAdd(&cnt[re], 1.0f);
            }
        }
        // ---- scatter tot_message (coalesced 256B per edge)
        #pragma unroll 4
        for (int e = 0; e < 16; ++e) {
            int re = __shfl(r_own, e);
            float mval = bf2f(Y[e * YPITCH + l]);
            atomicAdd(&totmsg[(long)re * 64 + l], mval);
        }
        // next iteration's first Y-write is preceded by a wave_fence (post-GEMM1)
    }
}

// ---------------- Kernel 3: finalize nodes
__global__ __launch_bounds__(256) void node_out_kernel(
    const float* __restrict__ x, const float* __restrict__ h, const float* __restrict__ v,
    const float* __restrict__ nn_w1, const float* __restrict__ nn_b1,
    const float* __restrict__ nn_w2, const float* __restrict__ nn_b2,
    const float* __restrict__ cnt, const double* __restrict__ totf,
    const float* __restrict__ totmsg,
    const float* __restrict__ gx, const float* __restrict__ gv,
    float* __restrict__ xout, float* __restrict__ vout, float* __restrict__ hout)
{
    __shared__ float w1s[128 * 64];
    __shared__ float w2s[64 * 64];
    __shared__ float b1s[64], b2s[64];
    int tid = threadIdx.x;
    for (int i = tid; i < 128 * 64; i += 256) w1s[i] = nn_w1[i];
    for (int i = tid; i < 64 * 64; i += 256) w2s[i] = nn_w2[i];
    if (tid < 64) { b1s[tid] = nn_b1[tid]; b2s[tid] = nn_b2[tid]; }
    __syncthreads();
    int wave = tid >> 6, lane = tid & 63;
    for (int node = blockIdx.x * 4 + wave; node < NN; node += gridDim.x * 4) {
        float hv = h[(long)node * 64 + lane];
        float tm = totmsg[(long)node * 64 + lane];
        float a = b1s[lane];
        #pragma unroll
        for (int k = 0; k < 64; ++k)
            a = fmaf(__shfl(hv, k), w1s[k * 64 + lane], a);
        #pragma unroll
        for (int k = 0; k < 64; ++k)
            a = fmaf(__shfl(tm, k), w1s[(64 + k) * 64 + lane], a);
        float y = silu(a);
        float o = b2s[lane];
        #pragma unroll
        for (int k = 0; k < 64; ++k)
            o = fmaf(__shfl(y, k), w2s[k * 64 + lane], o);
        hout[(long)node * 64 + lane] = o;
        if (lane < 3) {
            double dn = fmax((double)cnt[node], 1.0);
            double tf = totf[(long)node * 3 + lane] / dn;
            tf = fmin(fmax(tf, -100.0), 100.0);
            xout[(long)node * 3 + lane] = gx[node] * x[(long)node * 3 + lane] + (float)tf;
            vout[(long)node * 3 + lane] = gv[node] * v[(long)node * 3 + lane] + (float)tf;
        }
    }
}

extern "C" void kernel_launch(void* const* d_in, const int* in_sizes, int n_in,
                              void* d_out, int out_size, void* d_ws, size_t ws_size,
                              hipStream_t stream) {
    const float* x        = (const float*)d_in[0];
    const float* h        = (const float*)d_in[1];
    const float* v        = (const float*)d_in[2];
    const int*   eidx     = (const int*)d_in[3];
    const float* edge_fea = (const float*)d_in[4];
    const float* em_w1 = (const float*)d_in[5];  const float* em_b1 = (const float*)d_in[6];
    const float* em_w2 = (const float*)d_in[7];  const float* em_b2 = (const float*)d_in[8];
    const float* cn_w1 = (const float*)d_in[9];  const float* cn_b1 = (const float*)d_in[10];
    const float* cn_w2 = (const float*)d_in[11]; const float* cn_b2 = (const float*)d_in[12];
    const float* nn_w1 = (const float*)d_in[13]; const float* nn_b1 = (const float*)d_in[14];
    const float* nn_w2 = (const float*)d_in[15]; const float* nn_b2 = (const float*)d_in[16];
    const float* nx_w1 = (const float*)d_in[17]; const float* nx_b1 = (const float*)d_in[18];
    const float* nx_w2 = (const float*)d_in[19]; const float* nx_b2 = (const float*)d_in[20];
    const float* nv_w1 = (const float*)d_in[21]; const float* nv_b1 = (const float*)d_in[22];
    const float* nv_w2 = (const float*)d_in[23]; const float* nv_b2 = (const float*)d_in[24];

    const int* row = eidx;
    const int* col = eidx + NE;

    // Workspace layout (f32 units):
    //   cnt [0,N) | gx [N,2N) | gv [2N,3N) | totmsg [3N,67N) | totf(f64) [68N,74N)
    float*  ws     = (float*)d_ws;
    float*  cnt    = ws;
    float*  gx     = ws + NN;
    float*  gv     = ws + 2 * NN;
    float*  totmsg = ws + 3 * NN;
    double* totf   = (double*)(ws + 68 * NN);

    float* xout = (float*)d_out;
    float* vout = xout + NN * 3;
    float* hout = vout + NN * 3;

    hipMemsetAsync(d_ws, 0, (size_t)74 * NN * sizeof(float), stream);

    node_gate_kernel<<<1024, 256, 0, stream>>>(h, nx_w1, nx_b1, nx_w2, nx_b2,
                                               nv_w1, nv_b1, nv_w2, nv_b2, gx, gv);
    edge_kernel<<<1024, 256, 0, stream>>>(x, h, v, row, col, edge_fea,
                                          em_w1, em_b1, em_w2, em_b2,
                                          cn_w1, cn_b1, cn_w2, cn_b2,
                                          cnt, totf, totmsg);
    node_out_kernel<<<1024, 256, 0, stream>>>(x, h, v, nn_w1, nn_b1, nn_w2, nn_b2,
                                              cnt, totf, totmsg, gx, gv,
                                              xout, vout, hout);
}

// Round 12
// 585.478 us; speedup vs baseline: 2.9136x; 1.5627x over previous
//
#include <hip/hip_runtime.h>
#include <math.h>

#define NN 50000
#define NE 800000

typedef __attribute__((ext_vector_type(8))) short  s16x8;  // 8 bf16 (4 VGPRs) MFMA A/B frag
typedef __attribute__((ext_vector_type(4))) float  f32x4;  // MFMA C/D frag

__device__ __forceinline__ float silu(float x) { return x / (1.0f + expf(-x)); }

__device__ __forceinline__ unsigned short f2bf(float f) {  // RNE f32->bf16
    unsigned u = __builtin_bit_cast(unsigned, f);
    u += 0x7FFFu + ((u >> 16) & 1u);
    return (unsigned short)(u >> 16);
}
__device__ __forceinline__ float bf2f(unsigned short b) {
    unsigned u = ((unsigned)b) << 16;
    return __builtin_bit_cast(float, u);
}

// Zero-cost ordering fence: forbids compiler reordering of LDS ops across it.
// HW DS pipe is in-order per wave.
__device__ __forceinline__ void wave_fence() {
    asm volatile("" ::: "memory");
    __builtin_amdgcn_wave_barrier();
    asm volatile("" ::: "memory");
}

#define GP 72    // K pitch (bf16) for 64-K tiles
#define OP 136   // K pitch (bf16) for 128-K tiles (node_out)

// ---------------- Kernel 1: per-node gates via MFMA (16 nodes/wave)
// gx = silu(h@nx_w1+b).dot(nx_w2)+nx_b2 ; gv likewise with nv.
// All weights live in VGPR fragments; LDS only for the A tile.
__global__ __launch_bounds__(256, 4) void node_gate_kernel(
    const float* __restrict__ h,
    const float* __restrict__ nx_w1, const float* __restrict__ nx_b1,
    const float* __restrict__ nx_w2, const float* __restrict__ nx_b2,
    const float* __restrict__ nv_w1, const float* __restrict__ nv_b1,
    const float* __restrict__ nv_w2, const float* __restrict__ nv_b2,
    float* __restrict__ gx, float* __restrict__ gv)
{
    __shared__ unsigned short At[4][16 * GP];
    int tid = threadIdx.x;
    int wv = tid >> 6, l = tid & 63;
    int lm = l & 15, lg = l >> 4;

    // B-frags direct from global: B[k][n], lane holds n=16ns+lm, k=32kk+8lg+j
    s16x8 BX[2][4], BV[2][4];
    float bx1v[4], bv1v[4], wx2v[4], wv2v[4];
    #pragma unroll
    for (int ns = 0; ns < 4; ++ns) {
        int n = 16 * ns + lm;
        bx1v[ns] = nx_b1[n]; bv1v[ns] = nv_b1[n];
        wx2v[ns] = nx_w2[n]; wv2v[ns] = nv_w2[n];
        #pragma unroll
        for (int kk = 0; kk < 2; ++kk) {
            s16x8 bx, bv;
            #pragma unroll
            for (int j = 0; j < 8; ++j) {
                int k = 32 * kk + 8 * lg + j;
                bx[j] = (short)f2bf(nx_w1[k * 64 + n]);
                bv[j] = (short)f2bf(nv_w1[k * 64 + n]);
            }
            BX[kk][ns] = bx; BV[kk][ns] = bv;
        }
    }
    float bx2 = nx_b2[0], bv2 = nv_b2[0];
    unsigned short* A = At[wv];

    const int ntile = NN / 16;   // 3125
    for (int tile = blockIdx.x * 4 + wv; tile < ntile; tile += gridDim.x * 4) {
        int base = tile * 16;
        #pragma unroll 4
        for (int e = 0; e < 16; ++e)
            A[e * GP + l] = f2bf(h[(long)(base + e) * 64 + l]);
        wave_fence();

        f32x4 ax[4], av[4];
        #pragma unroll
        for (int ns = 0; ns < 4; ++ns) {
            float bx = bx1v[ns], bv = bv1v[ns];
            ax[ns] = (f32x4){bx, bx, bx, bx};
            av[ns] = (f32x4){bv, bv, bv, bv};
        }
        #pragma unroll
        for (int kk = 0; kk < 2; ++kk) {
            s16x8 af = *(const s16x8*)&A[lm * GP + 32 * kk + 8 * lg];
            #pragma unroll
            for (int ns = 0; ns < 4; ++ns) {
                ax[ns] = __builtin_amdgcn_mfma_f32_16x16x32_bf16(af, BX[kk][ns], ax[ns], 0, 0, 0);
                av[ns] = __builtin_amdgcn_mfma_f32_16x16x32_bf16(af, BV[kk][ns], av[ns], 0, 0, 0);
            }
        }
        // layer-2 dot + column reduce; D layout row=4lg+i, col=16ns+lm
        #pragma unroll
        for (int i = 0; i < 4; ++i) {
            float px = 0.0f, pv = 0.0f;
            #pragma unroll
            for (int ns = 0; ns < 4; ++ns) {
                px += silu(ax[ns][i]) * wx2v[ns];
                pv += silu(av[ns][i]) * wv2v[ns];
            }
            px += __shfl_xor(px, 1); pv += __shfl_xor(pv, 1);
            px += __shfl_xor(px, 2); pv += __shfl_xor(pv, 2);
            px += __shfl_xor(px, 4); pv += __shfl_xor(pv, 4);
            px += __shfl_xor(px, 8); pv += __shfl_xor(pv, 8);
            if (lm == 0) {
                gx[base + 4 * lg + i] = px + bx2;
                gv[base + 4 * lg + i] = pv + bv2;
            }
        }
        wave_fence();  // A reads done before next-iter staging
    }
}

// ---------------- Kernel 2: edge MLPs via MFMA + atomic scatter (the hot kernel)
//
// Per-wave 16-edge tiles. scalar_in K-permutation (vs reference order):
//   k' in [0,64)    -> h[row]   (orig rows 2..65)
//   k' in [64,128)  -> h[col]   (orig rows 66..129)
//   k' in [128,144) -> edge_fea (orig rows 130..145)
//   k' in [144,146) -> norms    (orig rows 0..1)
//   k' in [146,168) -> zero pad (K padded to 5 x 32 = 160, stride 168)
// em_w1 rows permuted identically at weight staging, so the product is exact.
#define KPAD   168   // A / w1t K stride (bf16), 16B-aligned (168*2=336)
#define YPITCH 72    // Y K stride (bf16)

__global__ __launch_bounds__(256, 3) void edge_kernel(
    const float* __restrict__ x, const float* __restrict__ h, const float* __restrict__ v,
    const int* __restrict__ row, const int* __restrict__ col,
    const float* __restrict__ edge_fea,
    const float* __restrict__ em_w1, const float* __restrict__ em_b1,
    const float* __restrict__ em_w2, const float* __restrict__ em_b2,
    const float* __restrict__ cn_w1, const float* __restrict__ cn_b1,
    const float* __restrict__ cn_w2, const float* __restrict__ cn_b2,
    float* __restrict__ cnt, double* __restrict__ totf, float* __restrict__ totmsg)
{
    __shared__ unsigned short w1t[64 * KPAD];     // [n][k'] = em_w1[orig(k')][n], bf16
    __shared__ float b1s[64], b2s[64], cb1s[64], c2s[64];
    __shared__ unsigned short Atile[4][16 * KPAD];    // per-wave A (bf16)
    __shared__ unsigned short Ybuf [4][16 * YPITCH];  // per-wave act/msg (bf16)

    int tid = threadIdx.x;
    // ---- one-time weight staging (transpose + K-permute + bf16)
    for (int idx = tid; idx < 64 * KPAD; idx += 256) {
        int n = idx / KPAD, kp = idx - n * KPAD;
        float val = 0.0f;
        if (kp < 146) { int ko = (kp < 144) ? (kp + 2) : (kp - 144); val = em_w1[ko * 64 + n]; }
        w1t[n * KPAD + kp] = f2bf(val);
    }
    if (tid < 64) { b1s[tid] = em_b1[tid]; b2s[tid] = em_b2[tid]; cb1s[tid] = cn_b1[tid]; c2s[tid] = cn_w2[tid]; }
    __syncthreads();
    float cb2 = cn_b2[0];

    int wv = tid >> 6, l = tid & 63;
    int lm = l & 15, lg = l >> 4;

    // ---- GEMM2/GEMM3 B-frags direct from global (one-time):
    //      lane holds B[k][n], n = 16*ns+lm, k = 32*kk+8*lg+j
    s16x8 B2[2][4], B3[2][4];
    #pragma unroll
    for (int kk = 0; kk < 2; ++kk)
        #pragma unroll
        for (int ns = 0; ns < 4; ++ns) {
            int n = 16 * ns + lm;
            s16x8 b2v, b3v;
            #pragma unroll
            for (int j = 0; j < 8; ++j) {
                int k = 32 * kk + 8 * lg + j;
                b2v[j] = (short)f2bf(em_w2[k * 64 + n]);
                b3v[j] = (short)f2bf(cn_w1[k * 64 + n]);
            }
            B2[kk][ns] = b2v; B3[kk][ns] = b3v;
        }

    unsigned short* A = Atile[wv];
    unsigned short* Y = Ybuf[wv];

    // zero-pad region k' in [146,168) — staging never touches it; write once
    if (lg == 0)
        for (int z = 146; z < KPAD; ++z) A[lm * KPAD + z] = 0;
    wave_fence();

    const int ntile = NE / 16;
    for (int tile = blockIdx.x * 4 + wv; tile < ntile; tile += gridDim.x * 4) {
        int base = tile * 16;
        // each lane owns edge (l&15); 4x redundant across lg groups (cheap, enables shfl)
        int r_own = row[base + lm];
        int c_own = col[base + lm];

        // geometry for own edge
        const float* xr = x + (long)r_own * 3; const float* xc = x + (long)c_own * 3;
        const float* vr = v + (long)r_own * 3; const float* vc = v + (long)c_own * 3;
        float rx = xr[0] - xc[0], ry = xr[1] - xc[1], rz = xr[2] - xc[2];
        float sx = vr[0] - vc[0], sy = vr[1] - vc[1], sz = vr[2] - vc[2];
        float nr = sqrtf(rx * rx + ry * ry + rz * rz);
        float nsv = sqrtf(sx * sx + sy * sy + sz * sz);
        if (lg == 0) {
            A[lm * KPAD + 144] = f2bf(nr);
            A[lm * KPAD + 145] = f2bf(nsv);
        }
        // h gather (coalesced 256B per row)
        #pragma unroll 4
        for (int e = 0; e < 16; ++e) {
            int re = __shfl(r_own, e);
            int ce = __shfl(c_own, e);
            A[e * KPAD + l]      = f2bf(h[(long)re * 64 + l]);
            A[e * KPAD + 64 + l] = f2bf(h[(long)ce * 64 + l]);
        }
        // edge features: 16 edges x 16 = 256 contiguous f32
        const float* efb = edge_fea + (long)base * 16;
        #pragma unroll
        for (int i = 0; i < 4; ++i) {
            int idx = i * 64 + l; int e = idx >> 4, j = idx & 15;
            A[e * KPAD + 128 + j] = f2bf(efb[idx]);
        }
        wave_fence();

        // ---- GEMM1: [16 x 160] x [160 x 64] -> acc (f32), bias-init
        f32x4 acc[4];
        #pragma unroll
        for (int ns = 0; ns < 4; ++ns) { float b = b1s[16 * ns + lm]; acc[ns] = (f32x4){b, b, b, b}; }
        #pragma unroll
        for (int kk = 0; kk < 5; ++kk) {
            s16x8 af = *(const s16x8*)&A[lm * KPAD + 32 * kk + 8 * lg];
            #pragma unroll
            for (int ns = 0; ns < 4; ++ns) {
                s16x8 bf = *(const s16x8*)&w1t[(16 * ns + lm) * KPAD + 32 * kk + 8 * lg];
                acc[ns] = __builtin_amdgcn_mfma_f32_16x16x32_bf16(af, bf, acc[ns], 0, 0, 0);
            }
        }
        wave_fence();  // (also orders prior-iter scatter Y-reads before Y writes below)
        // silu -> Y (bf16); D layout: row = 4*lg + i, col = 16*ns + lm
        #pragma unroll
        for (int ns = 0; ns < 4; ++ns)
            #pragma unroll
            for (int i = 0; i < 4; ++i)
                Y[(4 * lg + i) * YPITCH + 16 * ns + lm] = f2bf(silu(acc[ns][i]));
        wave_fence();

        // ---- GEMM2: y[16x64] x em_w2 -> message (silu)
        #pragma unroll
        for (int ns = 0; ns < 4; ++ns) { float b = b2s[16 * ns + lm]; acc[ns] = (f32x4){b, b, b, b}; }
        #pragma unroll
        for (int kk = 0; kk < 2; ++kk) {
            s16x8 af = *(const s16x8*)&Y[lm * YPITCH + 32 * kk + 8 * lg];
            #pragma unroll
            for (int ns = 0; ns < 4; ++ns)
                acc[ns] = __builtin_amdgcn_mfma_f32_16x16x32_bf16(af, B2[kk][ns], acc[ns], 0, 0, 0);
        }
        wave_fence();  // GEMM2 A-reads done before Y overwrite
        #pragma unroll
        for (int ns = 0; ns < 4; ++ns)
            #pragma unroll
            for (int i = 0; i < 4; ++i)
                Y[(4 * lg + i) * YPITCH + 16 * ns + lm] = f2bf(silu(acc[ns][i]));
        wave_fence();

        // ---- GEMM3: msg[16x64] x cn_w1 -> t; cm = dot(silu(t), cn_w2) + cb2
        #pragma unroll
        for (int ns = 0; ns < 4; ++ns) { float b = cb1s[16 * ns + lm]; acc[ns] = (f32x4){b, b, b, b}; }
        #pragma unroll
        for (int kk = 0; kk < 2; ++kk) {
            s16x8 af = *(const s16x8*)&Y[lm * YPITCH + 32 * kk + 8 * lg];
            #pragma unroll
            for (int ns = 0; ns < 4; ++ns)
                acc[ns] = __builtin_amdgcn_mfma_f32_16x16x32_bf16(af, B3[kk][ns], acc[ns], 0, 0, 0);
        }
        float cm[4];
        #pragma unroll
        for (int i = 0; i < 4; ++i) {
            float p = 0.0f;
            #pragma unroll
            for (int ns = 0; ns < 4; ++ns) p += silu(acc[ns][i]) * c2s[16 * ns + lm];
            p += __shfl_xor(p, 1); p += __shfl_xor(p, 2);
            p += __shfl_xor(p, 4); p += __shfl_xor(p, 8);
            cm[i] = p + cb2;   // cm for edge (4*lg + i), valid in all 16 lanes of group lg
        }

        // ---- scatter tot_f (f64) + cnt
        #pragma unroll
        for (int i = 0; i < 4; ++i) {
            int e = 4 * lg + i;
            float rxe = __shfl(rx, e), rye = __shfl(ry, e), rze = __shfl(rz, e);
            int   re  = __shfl(r_own, e);
            if (lm < 3) {
                float comp = (lm == 0) ? rxe : (lm == 1) ? rye : rze;
                atomicAdd(&totf[(long)re * 3 + lm], (double)(comp * cm[i]));
            } else if (lm == 3) {
                atomicAdd(&cnt[re], 1.0f);
            }
        }
        // ---- scatter tot_message (coalesced 256B per edge)
        #pragma unroll 4
        for (int e = 0; e < 16; ++e) {
            int re = __shfl(r_own, e);
            float mval = bf2f(Y[e * YPITCH + l]);
            atomicAdd(&totmsg[(long)re * 64 + l], mval);
        }
        // next iteration's first Y-write is preceded by a wave_fence (post-GEMM1)
    }
}

// ---------------- Kernel 3: finalize nodes via MFMA (16 nodes/wave)
// h_new = mlp([h, totmsg]; nn); x_new/v_new epilogue on 48 lanes.
__global__ __launch_bounds__(256, 3) void node_out_kernel(
    const float* __restrict__ x, const float* __restrict__ h, const float* __restrict__ v,
    const float* __restrict__ nn_w1, const float* __restrict__ nn_b1,
    const float* __restrict__ nn_w2, const float* __restrict__ nn_b2,
    const float* __restrict__ cnt, const double* __restrict__ totf,
    const float* __restrict__ totmsg,
    const float* __restrict__ gx, const float* __restrict__ gv,
    float* __restrict__ xout, float* __restrict__ vout, float* __restrict__ hout)
{
    __shared__ unsigned short w1t[64 * OP];       // [n][k] = nn_w1[k][n], k<128
    __shared__ unsigned short At[4][16 * OP];     // per-wave [h|totmsg] tile
    __shared__ unsigned short Yt[4][16 * GP];     // per-wave hidden (bf16)

    int tid = threadIdx.x;
    for (int idx = tid; idx < 64 * OP; idx += 256) {
        int n = idx / OP, k = idx - n * OP;
        w1t[idx] = f2bf(k < 128 ? nn_w1[k * 64 + n] : 0.0f);
    }
    __syncthreads();

    int wv = tid >> 6, l = tid & 63;
    int lm = l & 15, lg = l >> 4;

    // GEMM2 B-frags + biases direct from global
    s16x8 B2[2][4];
    float b1v[4], b2v[4];
    #pragma unroll
    for (int ns = 0; ns < 4; ++ns) {
        int n = 16 * ns + lm;
        b1v[ns] = nn_b1[n]; b2v[ns] = nn_b2[n];
        #pragma unroll
        for (int kk = 0; kk < 2; ++kk) {
            s16x8 b;
            #pragma unroll
            for (int j = 0; j < 8; ++j)
                b[j] = (short)f2bf(nn_w2[(32 * kk + 8 * lg + j) * 64 + n]);
            B2[kk][ns] = b;
        }
    }

    unsigned short* A = At[wv];
    unsigned short* Y = Yt[wv];

    const int ntile = NN / 16;
    for (int tile = blockIdx.x * 4 + wv; tile < ntile; tile += gridDim.x * 4) {
        int base = tile * 16;
        #pragma unroll 4
        for (int e = 0; e < 16; ++e) {
            A[e * OP + l]      = f2bf(h[(long)(base + e) * 64 + l]);
            A[e * OP + 64 + l] = f2bf(totmsg[(long)(base + e) * 64 + l]);
        }
        wave_fence();

        // GEMM1: [16x128] x [128x64]
        f32x4 acc[4];
        #pragma unroll
        for (int ns = 0; ns < 4; ++ns) { float b = b1v[ns]; acc[ns] = (f32x4){b, b, b, b}; }
        #pragma unroll
        for (int kk = 0; kk < 4; ++kk) {
            s16x8 af = *(const s16x8*)&A[lm * OP + 32 * kk + 8 * lg];
            #pragma unroll
            for (int ns = 0; ns < 4; ++ns) {
                s16x8 bf = *(const s16x8*)&w1t[(16 * ns + lm) * OP + 32 * kk + 8 * lg];
                acc[ns] = __builtin_amdgcn_mfma_f32_16x16x32_bf16(af, bf, acc[ns], 0, 0, 0);
            }
        }
        wave_fence();
        #pragma unroll
        for (int ns = 0; ns < 4; ++ns)
            #pragma unroll
            for (int i = 0; i < 4; ++i)
                Y[(4 * lg + i) * GP + 16 * ns + lm] = f2bf(silu(acc[ns][i]));
        wave_fence();

        // GEMM2: [16x64] x [64x64] -> hout (f32 store from accumulators)
        #pragma unroll
        for (int ns = 0; ns < 4; ++ns) { float b = b2v[ns]; acc[ns] = (f32x4){b, b, b, b}; }
        #pragma unroll
        for (int kk = 0; kk < 2; ++kk) {
            s16x8 af = *(const s16x8*)&Y[lm * GP + 32 * kk + 8 * lg];
            #pragma unroll
            for (int ns = 0; ns < 4; ++ns)
                acc[ns] = __builtin_amdgcn_mfma_f32_16x16x32_bf16(af, B2[kk][ns], acc[ns], 0, 0, 0);
        }
        #pragma unroll
        for (int ns = 0; ns < 4; ++ns)
            #pragma unroll
            for (int i = 0; i < 4; ++i)
                hout[(long)(base + 4 * lg + i) * 64 + 16 * ns + lm] = acc[ns][i];

        // x/v epilogue: 48 lanes cover 16 nodes x 3 comps
        if (l < 48) {
            int nd = base + l / 3, c = l - (l / 3) * 3;
            double dn = fmax((double)cnt[nd], 1.0);
            double tf = totf[(long)nd * 3 + c] / dn;
            tf = fmin(fmax(tf, -100.0), 100.0);
            xout[(long)nd * 3 + c] = gx[nd] * x[(long)nd * 3 + c] + (float)tf;
            vout[(long)nd * 3 + c] = gv[nd] * v[(long)nd * 3 + c] + (float)tf;
        }
        wave_fence();  // Y/A reads done before next-iter staging
    }
}

extern "C" void kernel_launch(void* const* d_in, const int* in_sizes, int n_in,
                              void* d_out, int out_size, void* d_ws, size_t ws_size,
                              hipStream_t stream) {
    const float* x        = (const float*)d_in[0];
    const float* h        = (const float*)d_in[1];
    const float* v        = (const float*)d_in[2];
    const int*   eidx     = (const int*)d_in[3];
    const float* edge_fea = (const float*)d_in[4];
    const float* em_w1 = (const float*)d_in[5];  const float* em_b1 = (const float*)d_in[6];
    const float* em_w2 = (const float*)d_in[7];  const float* em_b2 = (const float*)d_in[8];
    const float* cn_w1 = (const float*)d_in[9];  const float* cn_b1 = (const float*)d_in[10];
    const float* cn_w2 = (const float*)d_in[11]; const float* cn_b2 = (const float*)d_in[12];
    const float* nn_w1 = (const float*)d_in[13]; const float* nn_b1 = (const float*)d_in[14];
    const float* nn_w2 = (const float*)d_in[15]; const float* nn_b2 = (const float*)d_in[16];
    const float* nx_w1 = (const float*)d_in[17]; const float* nx_b1 = (const float*)d_in[18];
    const float* nx_w2 = (const float*)d_in[19]; const float* nx_b2 = (const float*)d_in[20];
    const float* nv_w1 = (const float*)d_in[21]; const float* nv_b1 = (const float*)d_in[22];
    const float* nv_w2 = (const float*)d_in[23]; const float* nv_b2 = (const float*)d_in[24];

    const int* row = eidx;
    const int* col = eidx + NE;

    // Workspace layout (f32 units):
    //   cnt [0,N) | gx [N,2N) | gv [2N,3N) | totmsg [3N,67N) | totf(f64) [68N,74N)
    float*  ws     = (float*)d_ws;
    float*  cnt    = ws;
    float*  gx     = ws + NN;
    float*  gv     = ws + 2 * NN;
    float*  totmsg = ws + 3 * NN;
    double* totf   = (double*)(ws + 68 * NN);

    float* xout = (float*)d_out;
    float* vout = xout + NN * 3;
    float* hout = vout + NN * 3;

    hipMemsetAsync(d_ws, 0, (size_t)74 * NN * sizeof(float), stream);

    node_gate_kernel<<<1024, 256, 0, stream>>>(h, nx_w1, nx_b1, nx_w2, nx_b2,
                                               nv_w1, nv_b1, nv_w2, nv_b2, gx, gv);
    edge_kernel<<<1024, 256, 0, stream>>>(x, h, v, row, col, edge_fea,
                                          em_w1, em_b1, em_w2, em_b2,
                                          cn_w1, cn_b1, cn_w2, cn_b2,
                                          cnt, totf, totmsg);
    node_out_kernel<<<1024, 256, 0, stream>>>(x, h, v, nn_w1, nn_b1, nn_w2, nn_b2,
                                              cnt, totf, totmsg, gx, gv,
                                              xout, vout, hout);
}